// Round 14
// baseline (6563.973 us; speedup 1.0000x reference)
//
#include <hip/hip_runtime.h>
#include <hip/hip_bf16.h>
#include <stdint.h>

#define DEVFN static __device__ __forceinline__

typedef __bf16 bf16x8 __attribute__((ext_vector_type(8)));
typedef float f32x4 __attribute__((ext_vector_type(4)));

DEVFN unsigned short f2bf(float f) {
  unsigned int u = __float_as_uint(f);
  u += 0x7FFFu + ((u >> 16) & 1u);
  return (unsigned short)(u >> 16);
}

DEVFN float softplus_f(float s) {
  return fmaxf(s, 0.0f) + log1pf(__expf(-fabsf(s)));
}

DEVFN void load_lds16(const void* g, void* l) {
  __builtin_amdgcn_global_load_lds(
      (const __attribute__((address_space(1))) void*)g,
      (__attribute__((address_space(3))) void*)l, 16, 0, 0);
}

// ---------------- fused prep: all weight fuses + x conv + biases -----------
DEVFN void fuse4(const float* __restrict__ m, const float* __restrict__ s,
                 const float* __restrict__ z, unsigned short* __restrict__ o, int i) {
  float4 mv = reinterpret_cast<const float4*>(m)[i];
  float4 sv = reinterpret_cast<const float4*>(s)[i];
  float4 zv = reinterpret_cast<const float4*>(z)[i];
  ushort4 ov;
  ov.x = f2bf(fmaf(softplus_f(sv.x), zv.x, mv.x));
  ov.y = f2bf(fmaf(softplus_f(sv.y), zv.y, mv.y));
  ov.z = f2bf(fmaf(softplus_f(sv.z), zv.z, mv.z));
  ov.w = f2bf(fmaf(softplus_f(sv.w), zv.w, mv.w));
  reinterpret_cast<ushort4*>(o)[i] = ov;
}

__global__ void prep_kernel(const float* __restrict__ mW0, const float* __restrict__ sW0,
                            const float* __restrict__ zW0,
                            const float* __restrict__ mW1, const float* __restrict__ sW1,
                            const float* __restrict__ zW1,
                            const float* __restrict__ mW2, const float* __restrict__ sW2,
                            const float* __restrict__ zW2,
                            const float* __restrict__ x,
                            const float* __restrict__ mb0, const float* __restrict__ sb0,
                            const float* __restrict__ zb0,
                            const float* __restrict__ mb1, const float* __restrict__ sb1,
                            const float* __restrict__ zb1,
                            const float* __restrict__ mb2, const float* __restrict__ sb2,
                            const float* __restrict__ zb2,
                            unsigned short* __restrict__ A0, unsigned short* __restrict__ A1,
                            unsigned short* __restrict__ A2, unsigned short* __restrict__ xb,
                            float* __restrict__ b0, float* __restrict__ b1,
                            float* __restrict__ b2) {
  const int N0 = 1048576;            // 4096*1024/4
  const int N1 = 4194304;            // 4096*4096/4
  const int N2 = 1048576;            // 1024*4096/4
  const int N3 = 2097152;            // 8192*1024/4
  const int N4 = 2304;               // 9216 bias scalars / 4
  const int NT = N0 + N1 + N2 + N3 + N4;
  int stride = gridDim.x * blockDim.x;
  for (int i = blockIdx.x * blockDim.x + threadIdx.x; i < NT; i += stride) {
    if (i < N0) {
      fuse4(mW0, sW0, zW0, A0, i);
    } else if (i < N0 + N1) {
      fuse4(mW1, sW1, zW1, A1, i - N0);
    } else if (i < N0 + N1 + N2) {
      fuse4(mW2, sW2, zW2, A2, i - N0 - N1);
    } else if (i < N0 + N1 + N2 + N3) {
      int k = i - N0 - N1 - N2;
      float4 v = reinterpret_cast<const float4*>(x)[k];
      ushort4 ov;
      ov.x = f2bf(v.x); ov.y = f2bf(v.y); ov.z = f2bf(v.z); ov.w = f2bf(v.w);
      reinterpret_cast<ushort4*>(xb)[k] = ov;
    } else {
      int k = (i - N0 - N1 - N2 - N3) * 4;
#pragma unroll
      for (int u = 0; u < 4; ++u) {
        int e = k + u;
        if (e < 4096)      b0[e]        = fmaf(softplus_f(sb0[e]),        zb0[e],        mb0[e]);
        else if (e < 8192) b1[e - 4096] = fmaf(softplus_f(sb1[e - 4096]), zb1[e - 4096], mb1[e - 4096]);
        else               b2[e - 8192] = fmaf(softplus_f(sb2[e - 8192]), zb2[e - 8192], mb2[e - 8192]);
      }
    }
  }
}

// ===========================================================================
// R14: B-from-global GEMM. BM=256, BK=32, BN = WN*64; 8 waves (8/WN M-rows
// x WN N-cols); 16x16x32 MFMA; wave tile 128x64 (WN=4) / 64x64 (WN=2).
//
// Change vs R13/R7: B-fragments are loaded GLOBAL->REG (weights are L2/L3
// resident; pattern = 16 rows x 64 contiguous B per frag, per-block B-tile
// 16 KB/tile -> L1 serves the wm-duplicate). B LDS slots deleted.
// Consequences (R11 traffic model, which retrodicted R4-R12):
//   LDS/tile: 96KB reads + 32KB writes (~1380 cyc, > MFMA 1242, binding)
//         ->  64KB reads + 16KB writes (~880 cyc, < MFMA) => MFMA-bound.
//   LDS 128KB -> 64KB => 2 blocks/CU, 4 waves/SIMD (launch_bounds(512,4)).
//
// Pipeline: R7's reg double-buffer, ring-of-4 A slots, stage lead 3.
// vmcnt ledger (mixed traffic; counts are order-independent within an
// iter): per iter issues 4 B-loads + 2 A-stage(t+3). At end of iter t,
// outstanding (worst case) = stage(t+2)[2] + B(t+1)[4] + stage(t+3)[2];
// vmcnt(6) drains stage(t+2) => slot (t+2)&3 landed; barrier publishes.
// Tail: no stage(t+3) -> vmcnt(4); staging done -> no explicit wait
// (compiler handles B-frag waits; these are plain loads).
//
// A-side T2 swizzle unchanged (verified 0 conflicts R4-R7,R13):
// LDS[r][c] = G[r][c ^ f(r)], f = (r>>1)&3, read chunk kg^f -> global
// k-group kg; B global read at kg*16 delivers the same k-group. T1
// bijective XCD swizzle (grids % 8 == 0).
// ===========================================================================
template <int WN, int RELU, int OUTBF16>
__global__ __launch_bounds__(512, 4) void gemm_bg_kernel(
    const unsigned short* __restrict__ X, const unsigned short* __restrict__ W,
    const float* __restrict__ bias, void* __restrict__ out,
    int M, int N, int K, int gx) {
  constexpr int BN = WN * 64;          // 256 or 128
  constexpr int MF = 2 * WN;           // A-frags per wave (8 or 4)
  __shared__ __align__(16) unsigned short lds[4 * 8192];  // 64 KiB, A ring-4

  const int nwg = gridDim.x;
  const int bid = blockIdx.x;
  const int nid = (bid & 7) * (nwg >> 3) + (bid >> 3);
  const int bx  = nid % gx;
  const int by  = nid / gx;

  const int tid  = threadIdx.x;
  const int lane = tid & 63;
  const int wv   = tid >> 6;                 // 0..7
  const int wm   = wv / WN;
  const int wn   = wv % WN;
  const int row0 = by * 256;
  const int col0 = bx * BN;
  const size_t ldb = (size_t)K * 2;

  // A staging: tile 16KB = 1024 chunks; thread covers chunks tid, tid+512.
  // chunk c -> row c>>2, chunkcol c&3; source chunkcol pre-swizzled.
  const int rS  = tid >> 2;                  // 0..127
  const int ccS = (tid & 3) ^ ((rS >> 1) & 3);
  const char* srcA = (const char*)X + (size_t)(row0 + rS) * ldb + ccS * 16;
  char* ldsb = (char*)lds;

  auto stageA = [&](int tt) {
    char* d = ldsb + (tt & 3) * 16384 + tid * 16;
    const char* s = srcA + (size_t)tt * 64;
    load_lds16(s, d);
    load_lds16(s + 128 * ldb, d + 8192);     // rows +128: swizzle invariant
  };

  const int l15 = lane & 15;
  const int kg  = lane >> 4;
  const int kgs = kg ^ ((l15 >> 1) & 3);
  const int aIdx = (wm * (32 * WN) + l15) * 32 + kgs * 8;   // ushort units
  const char* srcBW = (const char*)W + (size_t)(col0 + wn * 64 + l15) * ldb + kg * 16;

  f32x4 acc[MF][4];
#pragma unroll
  for (int i = 0; i < MF; ++i)
#pragma unroll
    for (int j = 0; j < 4; ++j)
      acc[i][j] = (f32x4){0.f, 0.f, 0.f, 0.f};

  auto readA = [&](int tt, bf16x8 (&aF)[MF]) {
    const int sa = (tt & 3) * 8192;
#pragma unroll
    for (int i = 0; i < MF; ++i) aF[i] = *(const bf16x8*)&lds[sa + aIdx + i * 512];
  };
  auto readBG = [&](int tt, bf16x8 (&bF)[4]) {
    const char* p = srcBW + (size_t)tt * 64;
#pragma unroll
    for (int j = 0; j < 4; ++j)
      bF[j] = *(const bf16x8*)(p + (size_t)(j * 16) * ldb);
  };
  auto mfmaTile = [&](bf16x8 (&aF)[MF], bf16x8 (&bF)[4]) {
    __builtin_amdgcn_s_setprio(1);
#pragma unroll
    for (int i = 0; i < MF; ++i)
#pragma unroll
      for (int j = 0; j < 4; ++j)
        acc[i][j] = __builtin_amdgcn_mfma_f32_16x16x32_bf16(aF[i], bF[j], acc[i][j], 0, 0, 0);
    __builtin_amdgcn_s_setprio(0);
  };

  const int nt = K >> 5;
  bf16x8 aA[MF], bA[4], aB[MF], bB[4];

  // prologue: stage tiles 0,1,2; publish 0,1 (stage(2) = 2 loads in flight);
  // preload frags(0)
  stageA(0); stageA(1); stageA(2);
  asm volatile("s_waitcnt vmcnt(2)" ::: "memory");
  __builtin_amdgcn_s_barrier();
  readA(0, aA); readBG(0, bA);

  auto body = [&](int t, bf16x8 (&aCur)[MF], bf16x8 (&bCur)[4],
                  bf16x8 (&aNxt)[MF], bf16x8 (&bNxt)[4]) {
    readA(t + 1, aNxt);
    readBG(t + 1, bNxt);
    if (t + 3 < nt) stageA(t + 3);
    mfmaTile(aCur, bCur);
    if (t + 3 < nt)      asm volatile("s_waitcnt vmcnt(6)" ::: "memory");
    else if (t + 2 < nt) asm volatile("s_waitcnt vmcnt(4)" ::: "memory");
    __builtin_amdgcn_s_barrier();  // publish t+2
  };

  for (int t = 0; t < nt - 2; t += 2) {
    body(t,     aA, bA, aB, bB);
    body(t + 1, aB, bB, aA, bA);
  }
  body(nt - 2, aA, bA, aB, bB);   // reads frags(nt-1)
  mfmaTile(aB, bB);               // compiler inserts the waits it needs

  // ---- epilogue: bias + optional ReLU ----
  float bv[4];
#pragma unroll
  for (int j = 0; j < 4; ++j) bv[j] = bias[col0 + wn * 64 + j * 16 + l15];

  const int rbase = row0 + wm * (32 * WN) + kg * 4;
  const int cbase = col0 + wn * 64 + l15;
#pragma unroll
  for (int i = 0; i < MF; ++i) {
#pragma unroll
    for (int j = 0; j < 4; ++j) {
#pragma unroll
      for (int r = 0; r < 4; ++r) {
        float v = acc[i][j][r] + bv[j];
        if (RELU) v = fmaxf(v, 0.0f);
        const size_t idx = (size_t)(rbase + i * 16 + r) * N + (cbase + j * 16);
        if (OUTBF16) ((unsigned short*)out)[idx] = f2bf(v);
        else         ((float*)out)[idx] = v;
      }
    }
  }
}

// ---------------------------------------------------------------------------
extern "C" void kernel_launch(void* const* d_in, const int* in_sizes, int n_in,
                              void* d_out, int out_size, void* d_ws, size_t ws_size,
                              hipStream_t stream) {
  const float* x   = (const float*)d_in[0];
  const float* mW0 = (const float*)d_in[1];
  const float* sW0 = (const float*)d_in[2];
  const float* zW0 = (const float*)d_in[3];
  const float* mb0 = (const float*)d_in[4];
  const float* sb0 = (const float*)d_in[5];
  const float* zb0 = (const float*)d_in[6];
  const float* mW1 = (const float*)d_in[7];
  const float* sW1 = (const float*)d_in[8];
  const float* zW1 = (const float*)d_in[9];
  const float* mb1 = (const float*)d_in[10];
  const float* sb1 = (const float*)d_in[11];
  const float* zb1 = (const float*)d_in[12];
  const float* mW2 = (const float*)d_in[13];
  const float* sW2 = (const float*)d_in[14];
  const float* zW2 = (const float*)d_in[15];
  const float* mb2 = (const float*)d_in[16];
  const float* sb2 = (const float*)d_in[17];
  const float* zb2 = (const float*)d_in[18];

  char* ws = (char*)d_ws;
  size_t off = 0;
  auto alloc = [&](size_t bytes) {
    char* p = ws + off;
    off += (bytes + 255) & ~(size_t)255;
    return p;
  };
  unsigned short* xb = (unsigned short*)alloc(8192ull * 1024 * 2);
  unsigned short* A0 = (unsigned short*)alloc(4096ull * 1024 * 2);
  unsigned short* A1 = (unsigned short*)alloc(4096ull * 4096 * 2);
  unsigned short* A2 = (unsigned short*)alloc(1024ull * 4096 * 2);
  unsigned short* h1 = (unsigned short*)alloc(8192ull * 4096 * 2);
  unsigned short* h2 = (unsigned short*)alloc(8192ull * 4096 * 2);
  float* b0 = (float*)alloc(4096 * 4);
  float* b1 = (float*)alloc(4096 * 4);
  float* b2 = (float*)alloc(1024 * 4);

  prep_kernel<<<4096, 256, 0, stream>>>(mW0, sW0, zW0, mW1, sW1, zW1,
                                        mW2, sW2, zW2, x,
                                        mb0, sb0, zb0, mb1, sb1, zb1,
                                        mb2, sb2, zb2,
                                        A0, A1, A2, xb, b0, b1, b2);

  // layer 0: [8192,1024] @ [4096,1024]^T -> relu -> h1 bf16   (BN=256, 512 wg)
  gemm_bg_kernel<4, 1, 1><<<512, 512, 0, stream>>>(xb, A0, b0, h1,
                                                   8192, 4096, 1024, 16);
  // layer 1: [8192,4096] @ [4096,4096]^T -> relu -> h2 bf16   (BN=256, 512 wg)
  gemm_bg_kernel<4, 1, 1><<<512, 512, 0, stream>>>(h1, A1, b1, h2,
                                                   8192, 4096, 4096, 16);
  // layer 2: [8192,4096] @ [1024,4096]^T -> d_out fp32        (BN=128, 256 wg)
  gemm_bg_kernel<2, 0, 0><<<256, 512, 0, stream>>>(h2, A2, b2, d_out,
                                                   8192, 1024, 4096, 8);
}

// Round 15
// 707.580 us; speedup vs baseline: 9.2766x; 9.2766x over previous
//
#include <hip/hip_runtime.h>
#include <hip/hip_bf16.h>
#include <stdint.h>

#define DEVFN static __device__ __forceinline__

typedef __bf16 bf16x8 __attribute__((ext_vector_type(8)));
typedef float f32x4 __attribute__((ext_vector_type(4)));

DEVFN unsigned short f2bf(float f) {
  unsigned int u = __float_as_uint(f);
  u += 0x7FFFu + ((u >> 16) & 1u);
  return (unsigned short)(u >> 16);
}

DEVFN float softplus_f(float s) {
  return fmaxf(s, 0.0f) + log1pf(__expf(-fabsf(s)));
}

DEVFN void load_lds16(const void* g, void* l) {
  __builtin_amdgcn_global_load_lds(
      (const __attribute__((address_space(1))) void*)g,
      (__attribute__((address_space(3))) void*)l, 16, 0, 0);
}

// ---------------- fused prep: all weight fuses + x conv + biases -----------
DEVFN void fuse4(const float* __restrict__ m, const float* __restrict__ s,
                 const float* __restrict__ z, unsigned short* __restrict__ o, int i) {
  float4 mv = reinterpret_cast<const float4*>(m)[i];
  float4 sv = reinterpret_cast<const float4*>(s)[i];
  float4 zv = reinterpret_cast<const float4*>(z)[i];
  ushort4 ov;
  ov.x = f2bf(fmaf(softplus_f(sv.x), zv.x, mv.x));
  ov.y = f2bf(fmaf(softplus_f(sv.y), zv.y, mv.y));
  ov.z = f2bf(fmaf(softplus_f(sv.z), zv.z, mv.z));
  ov.w = f2bf(fmaf(softplus_f(sv.w), zv.w, mv.w));
  reinterpret_cast<ushort4*>(o)[i] = ov;
}

__global__ void prep_kernel(const float* __restrict__ mW0, const float* __restrict__ sW0,
                            const float* __restrict__ zW0,
                            const float* __restrict__ mW1, const float* __restrict__ sW1,
                            const float* __restrict__ zW1,
                            const float* __restrict__ mW2, const float* __restrict__ sW2,
                            const float* __restrict__ zW2,
                            const float* __restrict__ x,
                            const float* __restrict__ mb0, const float* __restrict__ sb0,
                            const float* __restrict__ zb0,
                            const float* __restrict__ mb1, const float* __restrict__ sb1,
                            const float* __restrict__ zb1,
                            const float* __restrict__ mb2, const float* __restrict__ sb2,
                            const float* __restrict__ zb2,
                            unsigned short* __restrict__ A0, unsigned short* __restrict__ A1,
                            unsigned short* __restrict__ A2, unsigned short* __restrict__ xb,
                            float* __restrict__ b0, float* __restrict__ b1,
                            float* __restrict__ b2) {
  const int N0 = 1048576;            // 4096*1024/4
  const int N1 = 4194304;            // 4096*4096/4
  const int N2 = 1048576;            // 1024*4096/4
  const int N3 = 2097152;            // 8192*1024/4
  const int N4 = 2304;               // 9216 bias scalars / 4
  const int NT = N0 + N1 + N2 + N3 + N4;
  int stride = gridDim.x * blockDim.x;
  for (int i = blockIdx.x * blockDim.x + threadIdx.x; i < NT; i += stride) {
    if (i < N0) {
      fuse4(mW0, sW0, zW0, A0, i);
    } else if (i < N0 + N1) {
      fuse4(mW1, sW1, zW1, A1, i - N0);
    } else if (i < N0 + N1 + N2) {
      fuse4(mW2, sW2, zW2, A2, i - N0 - N1);
    } else if (i < N0 + N1 + N2 + N3) {
      int k = i - N0 - N1 - N2;
      float4 v = reinterpret_cast<const float4*>(x)[k];
      ushort4 ov;
      ov.x = f2bf(v.x); ov.y = f2bf(v.y); ov.z = f2bf(v.z); ov.w = f2bf(v.w);
      reinterpret_cast<ushort4*>(xb)[k] = ov;
    } else {
      int k = (i - N0 - N1 - N2 - N3) * 4;
#pragma unroll
      for (int u = 0; u < 4; ++u) {
        int e = k + u;
        if (e < 4096)      b0[e]        = fmaf(softplus_f(sb0[e]),        zb0[e],        mb0[e]);
        else if (e < 8192) b1[e - 4096] = fmaf(softplus_f(sb1[e - 4096]), zb1[e - 4096], mb1[e - 4096]);
        else               b2[e - 8192] = fmaf(softplus_f(sb2[e - 8192]), zb2[e - 8192], mb2[e - 8192]);
      }
    }
  }
}

// ===========================================================================
// R15: B-from-global GEMM, REGISTER BUDGET FIXED. Identical to R14 except
// __launch_bounds__(512,2).
//
// R14's failure was NOT the B-from-global theory: launch_bounds(512,4)
// demanded 8 waves/SIMD -> 64-VGPR cap -> compiler spilled acc+frags to
// scratch (VGPR_Count=64, WRITE_SIZE=13GB of spill traffic, MfmaUtil 2.4%).
// (512,2) is the R13-proven budget (128 VGPR, zero scratch with this exact
// register footprint). LDS = 64KB -> 2 blocks/CU still resident at 128
// VGPR -> 4 waves/SIMD of TLP PLUS the halved LDS traffic:
//   per 32-K tile: 64KB LDS reads + 16KB writes (~880 cyc) < MFMA 1242 cyc
//   => matrix pipe becomes the binding resource (R11 traffic model).
// B-fragments load GLOBAL->REG (weights L2/L3-resident; per-block B-slice
// 16KB/tile; wm-duplication served by L1).
//
// Pipeline: R7 reg double-buffer, ring-of-4 A slots, stage lead 3. vmcnt
// ledger (order-independent counting): per iter issues 4 B-loads + 2
// A-stage(t+3); at end of iter t outstanding <= stage(t+2)[2] + B(t+1)[4]
// + stage(t+3)[2]; vmcnt(6) guarantees stage(t+2) landed; barrier
// publishes. Tail: vmcnt(4) (no stage(t+3)); then none (compiler-managed).
//
// A-side T2 swizzle (verified 0 conflicts): stage pre-swizzles per-lane
// GLOBAL source chunk (cc ^= (row>>1)&3; LDS dest linear); read
// kg^((l15>>1)&3). T1 bijective XCD swizzle (grids % 8 == 0).
// ===========================================================================
template <int WN, int RELU, int OUTBF16>
__global__ __launch_bounds__(512, 2) void gemm_bg_kernel(
    const unsigned short* __restrict__ X, const unsigned short* __restrict__ W,
    const float* __restrict__ bias, void* __restrict__ out,
    int M, int N, int K, int gx) {
  constexpr int BN = WN * 64;          // 256 or 128
  constexpr int MF = 2 * WN;           // A-frags per wave (8 or 4)
  __shared__ __align__(16) unsigned short lds[4 * 8192];  // 64 KiB, A ring-4

  const int nwg = gridDim.x;
  const int bid = blockIdx.x;
  const int nid = (bid & 7) * (nwg >> 3) + (bid >> 3);
  const int bx  = nid % gx;
  const int by  = nid / gx;

  const int tid  = threadIdx.x;
  const int lane = tid & 63;
  const int wv   = tid >> 6;                 // 0..7
  const int wm   = wv / WN;
  const int wn   = wv % WN;
  const int row0 = by * 256;
  const int col0 = bx * BN;
  const size_t ldb = (size_t)K * 2;

  // A staging: tile 16KB = 1024 chunks; thread covers chunks tid, tid+512.
  const int rS  = tid >> 2;                  // 0..127
  const int ccS = (tid & 3) ^ ((rS >> 1) & 3);
  const char* srcA = (const char*)X + (size_t)(row0 + rS) * ldb + ccS * 16;
  char* ldsb = (char*)lds;

  auto stageA = [&](int tt) {
    char* d = ldsb + (tt & 3) * 16384 + tid * 16;
    const char* s = srcA + (size_t)tt * 64;
    load_lds16(s, d);
    load_lds16(s + 128 * ldb, d + 8192);     // rows +128: swizzle invariant
  };

  const int l15 = lane & 15;
  const int kg  = lane >> 4;
  const int kgs = kg ^ ((l15 >> 1) & 3);
  const int aIdx = (wm * (32 * WN) + l15) * 32 + kgs * 8;   // ushort units
  const char* srcBW = (const char*)W + (size_t)(col0 + wn * 64 + l15) * ldb + kg * 16;

  f32x4 acc[MF][4];
#pragma unroll
  for (int i = 0; i < MF; ++i)
#pragma unroll
    for (int j = 0; j < 4; ++j)
      acc[i][j] = (f32x4){0.f, 0.f, 0.f, 0.f};

  auto readA = [&](int tt, bf16x8 (&aF)[MF]) {
    const int sa = (tt & 3) * 8192;
#pragma unroll
    for (int i = 0; i < MF; ++i) aF[i] = *(const bf16x8*)&lds[sa + aIdx + i * 512];
  };
  auto readBG = [&](int tt, bf16x8 (&bF)[4]) {
    const char* p = srcBW + (size_t)tt * 64;
#pragma unroll
    for (int j = 0; j < 4; ++j)
      bF[j] = *(const bf16x8*)(p + (size_t)(j * 16) * ldb);
  };
  auto mfmaTile = [&](bf16x8 (&aF)[MF], bf16x8 (&bF)[4]) {
    __builtin_amdgcn_s_setprio(1);
#pragma unroll
    for (int i = 0; i < MF; ++i)
#pragma unroll
      for (int j = 0; j < 4; ++j)
        acc[i][j] = __builtin_amdgcn_mfma_f32_16x16x32_bf16(aF[i], bF[j], acc[i][j], 0, 0, 0);
    __builtin_amdgcn_s_setprio(0);
  };

  const int nt = K >> 5;
  bf16x8 aA[MF], bA[4], aB[MF], bB[4];

  // prologue: stage tiles 0,1,2; publish 0,1; preload frags(0)
  stageA(0); stageA(1); stageA(2);
  asm volatile("s_waitcnt vmcnt(2)" ::: "memory");
  __builtin_amdgcn_s_barrier();
  readA(0, aA); readBG(0, bA);

  auto body = [&](int t, bf16x8 (&aCur)[MF], bf16x8 (&bCur)[4],
                  bf16x8 (&aNxt)[MF], bf16x8 (&bNxt)[4]) {
    readA(t + 1, aNxt);
    readBG(t + 1, bNxt);
    if (t + 3 < nt) stageA(t + 3);
    mfmaTile(aCur, bCur);
    if (t + 3 < nt)      asm volatile("s_waitcnt vmcnt(6)" ::: "memory");
    else if (t + 2 < nt) asm volatile("s_waitcnt vmcnt(4)" ::: "memory");
    __builtin_amdgcn_s_barrier();  // publish t+2
  };

  for (int t = 0; t < nt - 2; t += 2) {
    body(t,     aA, bA, aB, bB);
    body(t + 1, aB, bB, aA, bA);
  }
  body(nt - 2, aA, bA, aB, bB);   // reads frags(nt-1)
  mfmaTile(aB, bB);               // compiler inserts the waits it needs

  // ---- epilogue: bias + optional ReLU ----
  float bv[4];
#pragma unroll
  for (int j = 0; j < 4; ++j) bv[j] = bias[col0 + wn * 64 + j * 16 + l15];

  const int rbase = row0 + wm * (32 * WN) + kg * 4;
  const int cbase = col0 + wn * 64 + l15;
#pragma unroll
  for (int i = 0; i < MF; ++i) {
#pragma unroll
    for (int j = 0; j < 4; ++j) {
#pragma unroll
      for (int r = 0; r < 4; ++r) {
        float v = acc[i][j][r] + bv[j];
        if (RELU) v = fmaxf(v, 0.0f);
        const size_t idx = (size_t)(rbase + i * 16 + r) * N + (cbase + j * 16);
        if (OUTBF16) ((unsigned short*)out)[idx] = f2bf(v);
        else         ((float*)out)[idx] = v;
      }
    }
  }
}

// ---------------------------------------------------------------------------
extern "C" void kernel_launch(void* const* d_in, const int* in_sizes, int n_in,
                              void* d_out, int out_size, void* d_ws, size_t ws_size,
                              hipStream_t stream) {
  const float* x   = (const float*)d_in[0];
  const float* mW0 = (const float*)d_in[1];
  const float* sW0 = (const float*)d_in[2];
  const float* zW0 = (const float*)d_in[3];
  const float* mb0 = (const float*)d_in[4];
  const float* sb0 = (const float*)d_in[5];
  const float* zb0 = (const float*)d_in[6];
  const float* mW1 = (const float*)d_in[7];
  const float* sW1 = (const float*)d_in[8];
  const float* zW1 = (const float*)d_in[9];
  const float* mb1 = (const float*)d_in[10];
  const float* sb1 = (const float*)d_in[11];
  const float* zb1 = (const float*)d_in[12];
  const float* mW2 = (const float*)d_in[13];
  const float* sW2 = (const float*)d_in[14];
  const float* zW2 = (const float*)d_in[15];
  const float* mb2 = (const float*)d_in[16];
  const float* sb2 = (const float*)d_in[17];
  const float* zb2 = (const float*)d_in[18];

  char* ws = (char*)d_ws;
  size_t off = 0;
  auto alloc = [&](size_t bytes) {
    char* p = ws + off;
    off += (bytes + 255) & ~(size_t)255;
    return p;
  };
  unsigned short* xb = (unsigned short*)alloc(8192ull * 1024 * 2);
  unsigned short* A0 = (unsigned short*)alloc(4096ull * 1024 * 2);
  unsigned short* A1 = (unsigned short*)alloc(4096ull * 4096 * 2);
  unsigned short* A2 = (unsigned short*)alloc(1024ull * 4096 * 2);
  unsigned short* h1 = (unsigned short*)alloc(8192ull * 4096 * 2);
  unsigned short* h2 = (unsigned short*)alloc(8192ull * 4096 * 2);
  float* b0 = (float*)alloc(4096 * 4);
  float* b1 = (float*)alloc(4096 * 4);
  float* b2 = (float*)alloc(1024 * 4);

  prep_kernel<<<4096, 256, 0, stream>>>(mW0, sW0, zW0, mW1, sW1, zW1,
                                        mW2, sW2, zW2, x,
                                        mb0, sb0, zb0, mb1, sb1, zb1,
                                        mb2, sb2, zb2,
                                        A0, A1, A2, xb, b0, b1, b2);

  // layer 0: [8192,1024] @ [4096,1024]^T -> relu -> h1 bf16   (BN=256, 512 wg)
  gemm_bg_kernel<4, 1, 1><<<512, 512, 0, stream>>>(xb, A0, b0, h1,
                                                   8192, 4096, 1024, 16);
  // layer 1: [8192,4096] @ [4096,4096]^T -> relu -> h2 bf16   (BN=256, 512 wg)
  gemm_bg_kernel<4, 1, 1><<<512, 512, 0, stream>>>(h1, A1, b1, h2,
                                                   8192, 4096, 4096, 16);
  // layer 2: [8192,4096] @ [1024,4096]^T -> d_out fp32        (BN=128, 256 wg)
  gemm_bg_kernel<2, 0, 0><<<256, 512, 0, stream>>>(h2, A2, b2, d_out,
                                                   8192, 1024, 4096, 8);
}

// Round 16
// 468.397 us; speedup vs baseline: 14.0137x; 1.5106x over previous
//
#include <hip/hip_runtime.h>
#include <hip/hip_bf16.h>
#include <stdint.h>

#define DEVFN static __device__ __forceinline__

typedef __bf16 bf16x8 __attribute__((ext_vector_type(8)));
typedef float f32x4 __attribute__((ext_vector_type(4)));

DEVFN unsigned short f2bf(float f) {
  unsigned int u = __float_as_uint(f);
  u += 0x7FFFu + ((u >> 16) & 1u);
  return (unsigned short)(u >> 16);
}

DEVFN float softplus_f(float s) {
  return fmaxf(s, 0.0f) + log1pf(__expf(-fabsf(s)));
}

DEVFN void load_lds16(const void* g, void* l) {
  __builtin_amdgcn_global_load_lds(
      (const __attribute__((address_space(1))) void*)g,
      (__attribute__((address_space(3))) void*)l, 16, 0, 0);
}

// ---------------- fused prep, block-range partitioned ----------------------
// Blocks [0,512): W0 fuse; [512,2560): W1; [2560,3072): W2; [3072,4096):
// x conv; [4096,4104): biases. Region chosen ONCE per block (uniform);
// inner loops are branch-free grid-strides over the region.
DEVFN void fuse_region(const float* __restrict__ m, const float* __restrict__ s,
                       const float* __restrict__ z, unsigned short* __restrict__ o,
                       int n4, int lbid, int nblk) {
  const int stride = nblk * 256;
  for (int i = lbid * 256 + (int)threadIdx.x; i < n4; i += stride) {
    float4 mv = reinterpret_cast<const float4*>(m)[i];
    float4 sv = reinterpret_cast<const float4*>(s)[i];
    float4 zv = reinterpret_cast<const float4*>(z)[i];
    ushort4 ov;
    ov.x = f2bf(fmaf(softplus_f(sv.x), zv.x, mv.x));
    ov.y = f2bf(fmaf(softplus_f(sv.y), zv.y, mv.y));
    ov.z = f2bf(fmaf(softplus_f(sv.z), zv.z, mv.z));
    ov.w = f2bf(fmaf(softplus_f(sv.w), zv.w, mv.w));
    reinterpret_cast<ushort4*>(o)[i] = ov;
  }
}

__global__ void prep_kernel(const float* __restrict__ mW0, const float* __restrict__ sW0,
                            const float* __restrict__ zW0,
                            const float* __restrict__ mW1, const float* __restrict__ sW1,
                            const float* __restrict__ zW1,
                            const float* __restrict__ mW2, const float* __restrict__ sW2,
                            const float* __restrict__ zW2,
                            const float* __restrict__ x,
                            const float* __restrict__ mb0, const float* __restrict__ sb0,
                            const float* __restrict__ zb0,
                            const float* __restrict__ mb1, const float* __restrict__ sb1,
                            const float* __restrict__ zb1,
                            const float* __restrict__ mb2, const float* __restrict__ sb2,
                            const float* __restrict__ zb2,
                            unsigned short* __restrict__ A0, unsigned short* __restrict__ A1,
                            unsigned short* __restrict__ A2, unsigned short* __restrict__ xb,
                            float* __restrict__ b0, float* __restrict__ b1,
                            float* __restrict__ b2) {
  const int bid = blockIdx.x;
  if (bid < 512) {
    fuse_region(mW0, sW0, zW0, A0, 1048576, bid, 512);
  } else if (bid < 2560) {
    fuse_region(mW1, sW1, zW1, A1, 4194304, bid - 512, 2048);
  } else if (bid < 3072) {
    fuse_region(mW2, sW2, zW2, A2, 1048576, bid - 2560, 512);
  } else if (bid < 4096) {
    const int lbid = bid - 3072;
    for (int i = lbid * 256 + (int)threadIdx.x; i < 2097152; i += 1024 * 256) {
      float4 v = reinterpret_cast<const float4*>(x)[i];
      ushort4 ov;
      ov.x = f2bf(v.x); ov.y = f2bf(v.y); ov.z = f2bf(v.z); ov.w = f2bf(v.w);
      reinterpret_cast<ushort4*>(xb)[i] = ov;
    }
  } else {
    const int lbid = bid - 4096;
    for (int e = lbid * 256 + (int)threadIdx.x; e < 9216; e += 8 * 256) {
      if (e < 4096)      b0[e]        = fmaf(softplus_f(sb0[e]),        zb0[e],        mb0[e]);
      else if (e < 8192) b1[e - 4096] = fmaf(softplus_f(sb1[e - 4096]), zb1[e - 4096], mb1[e - 4096]);
      else               b2[e - 8192] = fmaf(softplus_f(sb2[e - 8192]), zb2[e - 8192], mb2[e - 8192]);
    }
  }
}

// ===========================================================================
// Pipelined GEMM — R13-EXACT (measured best across 10 structural variants:
// G1 239.3us / 1148 TF, MfmaUtil 52.6%, bank conflicts 0, VGPR 128).
// BM=256, BK=32, BN = WN*64 (WN=4 -> 256, WN=2 -> 128). 8 waves as
// (8/WN) M-rows x WN N-cols; 16x16x32 MFMA; wave tile 128x64 (WN=4) —
// feasible optimum of LDS-reads/MFMA under the 256-VGPR limit (R12).
// B stays in LDS (R15: B-from-global is uncoalesced at 8KB row stride,
// MfmaUtil 30% — refuted).
//
// Body order: readFrags(t+1) -> stage(t+3) -> MFMA(t). Ring-of-4 slots,
// stage lead 3: reads (t+1)&3, source t&3, landing (t+2)&3, staging
// (t+3)&3 all distinct. vmcnt(LPT) at tile end leaves only stage(t+3)
// in flight => t+2 landed; barrier publishes. No lgkm pins (compiler
// emits fine-grained counted lgkmcnt; pins measured harmful R6).
// T2 swizzle (verified 0 conflicts): stage pre-swizzles per-lane GLOBAL
// source 16B-chunk (cc ^= (row>>1)&3; LDS dest linear, rule 21); read
// kg ^ ((l15>>1)&3). T1 bijective XCD swizzle (grids % 8 == 0).
// ===========================================================================
template <int WN, int RELU, int OUTBF16>
__global__ __launch_bounds__(512, 2) void gemm_pipe_kernel(
    const unsigned short* __restrict__ X, const unsigned short* __restrict__ W,
    const float* __restrict__ bias, void* __restrict__ out,
    int M, int N, int K, int gx) {
  constexpr int BN  = WN * 64;         // 256 or 128
  constexpr int MF  = 2 * WN;          // A-frags per wave (8 or 4)
  constexpr int LPT = (WN == 4) ? 4 : 3;  // global_load_lds per tile per thread
  constexpr int BS  = BN * 32;         // B slot size, ushorts
  __shared__ __align__(16) unsigned short lds[32768 + 4 * BS];

  const int nwg = gridDim.x;
  const int bid = blockIdx.x;
  const int nid = (bid & 7) * (nwg >> 3) + (bid >> 3);
  const int bx  = nid % gx;
  const int by  = nid / gx;

  const int tid  = threadIdx.x;
  const int lane = tid & 63;
  const int wv   = tid >> 6;                 // 0..7
  const int wm   = wv / WN;
  const int wn   = wv % WN;
  const int row0 = by * 256;
  const int col0 = bx * BN;
  const size_t ldb = (size_t)K * 2;

  const int cA  = wv * 64 + lane;
  const int rS  = cA >> 2;
  const int ccS = (cA & 3) ^ ((rS >> 1) & 3);
  const char* srcA = (const char*)X + (size_t)(row0 + rS) * ldb + ccS * 16;
  const char* srcB = (const char*)W + (size_t)(col0 + rS) * ldb + ccS * 16;
  char* ldsb = (char*)lds;

  auto stageA = [&](int tt) {
    char* d = ldsb + (tt & 3) * 16384 + wv * 1024;
    const char* s = srcA + (size_t)tt * 64;
    load_lds16(s, d);
    load_lds16(s + 128 * ldb, d + 8192);     // rows +128: swizzle invariant
  };
  auto stageB = [&](int tt) {
    char* d = ldsb + 65536 + (tt & 3) * (BS * 2) + wv * 1024;
    const char* s = srcB + (size_t)tt * 64;
    load_lds16(s, d);
    if constexpr (WN == 4) load_lds16(s + 128 * ldb, d + 8192);
  };

  const int l15 = lane & 15;
  const int kg  = lane >> 4;
  const int kgs = kg ^ ((l15 >> 1) & 3);
  const int aIdx = (wm * (32 * WN) + l15) * 32 + kgs * 8;
  const int bIdx = (wn * 64 + l15) * 32 + kgs * 8;

  f32x4 acc[MF][4];
#pragma unroll
  for (int i = 0; i < MF; ++i)
#pragma unroll
    for (int j = 0; j < 4; ++j)
      acc[i][j] = (f32x4){0.f, 0.f, 0.f, 0.f};

  auto readFrags = [&](int tt, bf16x8 (&aF)[MF], bf16x8 (&bF)[4]) {
    const int sa = (tt & 3) * 8192;
    const int sb = 32768 + (tt & 3) * BS;
#pragma unroll
    for (int i = 0; i < MF; ++i) aF[i] = *(const bf16x8*)&lds[sa + aIdx + i * 512];
#pragma unroll
    for (int j = 0; j < 4; ++j)  bF[j] = *(const bf16x8*)&lds[sb + bIdx + j * 512];
  };
  auto mfmaTile = [&](bf16x8 (&aF)[MF], bf16x8 (&bF)[4]) {
    __builtin_amdgcn_s_setprio(1);
#pragma unroll
    for (int i = 0; i < MF; ++i)
#pragma unroll
      for (int j = 0; j < 4; ++j)
        acc[i][j] = __builtin_amdgcn_mfma_f32_16x16x32_bf16(aF[i], bF[j], acc[i][j], 0, 0, 0);
    __builtin_amdgcn_s_setprio(0);
  };

  const int nt = K >> 5;
  bf16x8 aA[MF], bA[4], aB[MF], bB[4];

  // prologue: stage tiles 0,1,2; publish 0,1; preload frags(0)
  stageA(0); stageB(0); stageA(1); stageB(1); stageA(2); stageB(2);
  asm volatile("s_waitcnt vmcnt(%0)" :: "i"(LPT) : "memory");  // t0,t1 landed
  __builtin_amdgcn_s_barrier();
  readFrags(0, aA, bA);

  auto body = [&](int t, bf16x8 (&aCur)[MF], bf16x8 (&bCur)[4],
                  bf16x8 (&aNxt)[MF], bf16x8 (&bNxt)[4]) {
    readFrags(t + 1, aNxt, bNxt);
    if (t + 3 < nt) { stageA(t + 3); stageB(t + 3); }
    mfmaTile(aCur, bCur);
    if (t + 3 < nt) asm volatile("s_waitcnt vmcnt(%0)" :: "i"(LPT) : "memory");
    else            asm volatile("s_waitcnt vmcnt(0)" ::: "memory");
    __builtin_amdgcn_s_barrier();  // publish t+2
  };

  for (int t = 0; t < nt - 2; t += 2) {
    body(t,     aA, bA, aB, bB);
    body(t + 1, aB, bB, aA, bA);
  }
  body(nt - 2, aA, bA, aB, bB);   // reads frags(nt-1); drains staging
  mfmaTile(aB, bB);               // compiler inserts the lgkm wait it needs

  // ---- epilogue: bias + optional ReLU ----
  float bv[4];
#pragma unroll
  for (int j = 0; j < 4; ++j) bv[j] = bias[col0 + wn * 64 + j * 16 + l15];

  const int rbase = row0 + wm * (32 * WN) + kg * 4;
  const int cbase = col0 + wn * 64 + l15;
#pragma unroll
  for (int i = 0; i < MF; ++i) {
#pragma unroll
    for (int j = 0; j < 4; ++j) {
#pragma unroll
      for (int r = 0; r < 4; ++r) {
        float v = acc[i][j][r] + bv[j];
        if (RELU) v = fmaxf(v, 0.0f);
        const size_t idx = (size_t)(rbase + i * 16 + r) * N + (cbase + j * 16);
        if (OUTBF16) ((unsigned short*)out)[idx] = f2bf(v);
        else         ((float*)out)[idx] = v;
      }
    }
  }
}

// ---------------------------------------------------------------------------
extern "C" void kernel_launch(void* const* d_in, const int* in_sizes, int n_in,
                              void* d_out, int out_size, void* d_ws, size_t ws_size,
                              hipStream_t stream) {
  const float* x   = (const float*)d_in[0];
  const float* mW0 = (const float*)d_in[1];
  const float* sW0 = (const float*)d_in[2];
  const float* zW0 = (const float*)d_in[3];
  const float* mb0 = (const float*)d_in[4];
  const float* sb0 = (const float*)d_in[5];
  const float* zb0 = (const float*)d_in[6];
  const float* mW1 = (const float*)d_in[7];
  const float* sW1 = (const float*)d_in[8];
  const float* zW1 = (const float*)d_in[9];
  const float* mb1 = (const float*)d_in[10];
  const float* sb1 = (const float*)d_in[11];
  const float* zb1 = (const float*)d_in[12];
  const float* mW2 = (const float*)d_in[13];
  const float* sW2 = (const float*)d_in[14];
  const float* zW2 = (const float*)d_in[15];
  const float* mb2 = (const float*)d_in[16];
  const float* sb2 = (const float*)d_in[17];
  const float* zb2 = (const float*)d_in[18];

  char* ws = (char*)d_ws;
  size_t off = 0;
  auto alloc = [&](size_t bytes) {
    char* p = ws + off;
    off += (bytes + 255) & ~(size_t)255;
    return p;
  };
  unsigned short* xb = (unsigned short*)alloc(8192ull * 1024 * 2);
  unsigned short* A0 = (unsigned short*)alloc(4096ull * 1024 * 2);
  unsigned short* A1 = (unsigned short*)alloc(4096ull * 4096 * 2);
  unsigned short* A2 = (unsigned short*)alloc(1024ull * 4096 * 2);
  unsigned short* h1 = (unsigned short*)alloc(8192ull * 4096 * 2);
  unsigned short* h2 = (unsigned short*)alloc(8192ull * 4096 * 2);
  float* b0 = (float*)alloc(4096 * 4);
  float* b1 = (float*)alloc(4096 * 4);
  float* b2 = (float*)alloc(1024 * 4);

  prep_kernel<<<4104, 256, 0, stream>>>(mW0, sW0, zW0, mW1, sW1, zW1,
                                        mW2, sW2, zW2, x,
                                        mb0, sb0, zb0, mb1, sb1, zb1,
                                        mb2, sb2, zb2,
                                        A0, A1, A2, xb, b0, b1, b2);

  // layer 0: [8192,1024] @ [4096,1024]^T -> relu -> h1 bf16   (BN=256, 512 wg)
  gemm_pipe_kernel<4, 1, 1><<<512, 512, 0, stream>>>(xb, A0, b0, h1,
                                                     8192, 4096, 1024, 16);
  // layer 1: [8192,4096] @ [4096,4096]^T -> relu -> h2 bf16   (BN=256, 512 wg)
  gemm_pipe_kernel<4, 1, 1><<<512, 512, 0, stream>>>(h1, A1, b1, h2,
                                                     8192, 4096, 4096, 16);
  // layer 2: [8192,4096] @ [1024,4096]^T -> d_out fp32        (BN=128, 256 wg)
  gemm_pipe_kernel<2, 0, 0><<<256, 512, 0, stream>>>(h2, A2, b2, d_out,
                                                     8192, 1024, 4096, 8);
}